// Round 7
// baseline (36575.034 us; speedup 1.0000x reference)
//
#include <hip/hip_runtime.h>
#include <stdint.h>
#include <stddef.h>

#define B_ 16
#define T_ 4096
#define D_ 256
#define H_ 512
#define G3_ 1536

// ws layout
#define OFF_IG   ((size_t)0)                       // igates f16: 65536*1536*2 = 201326592
#define OFF_WT   ((size_t)201326592)               // W_ih^T packed float4: 256*1536*4 = 1572864
#define OFF_MB   ((size_t)202899456)               // mailbox: 2*16*512*4 = 65536
#define WS_NEED  ((size_t)203161600)

#define MB_PAR   (B_ * H_)                          // words per parity buffer

typedef _Float16 h2_t __attribute__((ext_vector_type(2)));

#if defined(__has_builtin)
#if __has_builtin(__builtin_amdgcn_fdot2)
#define HAVE_FDOT2 1
#endif
#endif

__device__ __forceinline__ float fdot2f(uint32_t w, uint32_t h, float acc) {
  union { uint32_t u; h2_t v; } a, b;
  a.u = w; b.u = h;
#ifdef HAVE_FDOT2
  return __builtin_amdgcn_fdot2(a.v, b.v, acc, false);
#else
  return fmaf((float)a.v.x, (float)b.v.x, fmaf((float)a.v.y, (float)b.v.y, acc));
#endif
}

__device__ __forceinline__ uint32_t packh2(float a, float b) {
  union { h2_t v; uint32_t u; } x;
  x.v.x = (_Float16)a; x.v.y = (_Float16)b;
  return x.u;
}

__device__ __forceinline__ uint32_t f16bits(float a) {
  union { _Float16 h; uint16_t u; } x;
  x.h = (_Float16)a;
  return (uint32_t)x.u;
}

__device__ __forceinline__ float h2f(uint16_t u) {
  union { _Float16 h; uint16_t u; } x;
  x.u = u;
  return (float)x.h;
}

__device__ __forceinline__ float sigmoidf_(float x) {
  return 1.0f / (1.0f + __expf(-x));
}

__device__ __forceinline__ float tanhf_(float x) {
  x = fminf(fmaxf(x, -15.0f), 15.0f);
  float e = __expf(-2.0f * x);
  return (1.0f - e) / (1.0f + e);
}

// ---------------- Kernel 1: transpose+pack W_ih into [d/4][g] float4 ----------------
__global__ void __launch_bounds__(256) wt_kernel(const float* __restrict__ W, float4* __restrict__ Wt4) {
  int idx = blockIdx.x * 256 + threadIdx.x;   // over 1536*64
  if (idx >= G3_ * 64) return;
  int g = idx % G3_;
  int d4 = idx / G3_;
  float4 v = *(const float4*)(W + (size_t)g * D_ + 4 * d4);
  Wt4[(size_t)d4 * G3_ + g] = v;
}

// ---------------- Kernel 2: igates = xs @ W_ih^T + b  -> f16 ----------------
__global__ void __launch_bounds__(256) ig_kernel(const float* __restrict__ xs,
                                                 const float* __restrict__ Wt,
                                                 const float* __restrict__ bias,
                                                 _Float16* __restrict__ ig) {
  __shared__ float xls[16 * 256];
  const int m0 = blockIdx.x * 16;
  const int tid = threadIdx.x;

  const float4* xsrc = (const float4*)(xs + (size_t)m0 * D_);
  float4* xdst = (float4*)xls;
#pragma unroll
  for (int k = 0; k < 4; ++k) xdst[tid + 256 * k] = xsrc[tid + 256 * k];
  __syncthreads();

  float acc[6][16];
#pragma unroll
  for (int k = 0; k < 6; ++k)
#pragma unroll
    for (int m = 0; m < 16; ++m) acc[k][m] = 0.0f;

  const float4* Wt4 = (const float4*)Wt;
  const float4* lds4 = (const float4*)xls;

  for (int d4 = 0; d4 < 64; ++d4) {
    float4 w[6];
#pragma unroll
    for (int k = 0; k < 6; ++k) w[k] = Wt4[(size_t)d4 * G3_ + tid + 256 * k];
#pragma unroll
    for (int m = 0; m < 16; ++m) {
      float4 xv = lds4[m * 64 + d4];
#pragma unroll
      for (int k = 0; k < 6; ++k) {
        acc[k][m] = fmaf(w[k].x, xv.x, acc[k][m]);
        acc[k][m] = fmaf(w[k].y, xv.y, acc[k][m]);
        acc[k][m] = fmaf(w[k].z, xv.z, acc[k][m]);
        acc[k][m] = fmaf(w[k].w, xv.w, acc[k][m]);
      }
    }
  }

#pragma unroll
  for (int k = 0; k < 6; ++k) {
    float bb = bias[tid + 256 * k];
#pragma unroll
    for (int m = 0; m < 16; ++m) {
      ig[(size_t)(m0 + m) * G3_ + tid + 256 * k] = (_Float16)(acc[k][m] + bb);
    }
  }
}

// ---------------- Kernel 3: persistent recurrence, wave-autonomous ----------------
// 256 WGs x 256 threads = 1024 waves. Wave gw: batch b = gw>>6, wave-in-batch
// wb = gw&63 owns columns [wb*8, wb*8+8). Lane l: q = l&7 (K-slice of 64),
// column j = wb*8 + (l>>3). Weights: rows {j, j+512, j+1024} x K[q*64,+64)
// as 96 packed-f16 VGPRs.
// Exchange: ONE shared per-batch mailbox of tagged words (tag<<16)|f16(h),
// double-buffered by parity. Producer lane (q==0): 1 agent-scope atomic store
// per column. Consumer lane polls its 64 words with 16 dwordx4 AGENT-scope
// (sc1 ONLY — sc0+sc1 is SYSTEM scope and reads stale past the MALL; R6 bug)
// loads in flight + one vmcnt(0); all-64 tag check via XOR/OR reduce.
// Sticky per-lane hedge: if the asm poll fails 256 rounds, demote permanently
// to a batched __hip_atomic_load(AGENT) retry loop (round-2-proven primitive).
// No __syncthreads in the loop; only intra-wave shfl coupling.
// Race bound: a slot is overwritten (tag t+2) only after ALL waves published
// t+1, which requires every wave to have finished reading tag t.
__global__ void __launch_bounds__(256, 1) rec_kernel(const _Float16* __restrict__ ig,
                                                     const float* __restrict__ Whh,
                                                     const float* __restrict__ bn,
                                                     uint32_t* __restrict__ mb,
                                                     float* __restrict__ out) {
  const int tid = threadIdx.x;
  const int gw = (blockIdx.x << 2) + (tid >> 6);   // 0..1023
  const int l = tid & 63;
  const int b = gw >> 6;         // 0..15
  const int wb = gw & 63;        // 0..63
  const int q = l & 7;           // K-slice
  const int clc = l >> 3;        // 0..7
  const int j = wb * 8 + clc;    // 0..511

  // ---- load + pack weights into registers (96 dwords) ----
  uint32_t wr[32], wz[32], wn[32];
  {
    const float4* s0 = (const float4*)(Whh + (size_t)j * H_ + q * 64);
    const float4* s1 = (const float4*)(Whh + (size_t)(j + H_) * H_ + q * 64);
    const float4* s2 = (const float4*)(Whh + (size_t)(j + 2 * H_) * H_ + q * 64);
#pragma unroll
    for (int i = 0; i < 16; ++i) {
      float4 v0 = s0[i]; wr[2 * i] = packh2(v0.x, v0.y); wr[2 * i + 1] = packh2(v0.z, v0.w);
      float4 v1 = s1[i]; wz[2 * i] = packh2(v1.x, v1.y); wz[2 * i + 1] = packh2(v1.z, v1.w);
      float4 v2 = s2[i]; wn[2 * i] = packh2(v2.x, v2.y); wn[2 * i + 1] = packh2(v2.z, v2.w);
    }
  }
  const float bnj = bn[j];

  // mailbox addresses
  uint32_t* box0 = mb + (size_t)b * H_;                 // parity 0
  uint32_t* poll_base0 = box0 + q * 64;                 // my 64 words (256B aligned)

  const uint16_t* ig16 = (const uint16_t*)ig;
  size_t igbase = (size_t)b * T_ * G3_;

  // ig prefetch pipeline: cur(t), nxt(t+1); fut(t+2) issued post-detection
  uint16_t cr = ig16[igbase + j];
  uint16_t cz = ig16[igbase + j + H_];
  uint16_t cn = ig16[igbase + j + 2 * H_];
  uint16_t nr = ig16[igbase + G3_ + j];
  uint16_t nz = ig16[igbase + G3_ + j + H_];
  uint16_t nn2 = ig16[igbase + G3_ + j + 2 * H_];

  float hprev = 0.0f;
  bool fast = true;    // per-lane sticky read-path mode

  for (int t = 0; t < T_; ++t) {
    float ar, az, an;
    uint16_t fr = 0, fz = 0, fn = 0;

    if (t > 0) {
      uint32_t* pb = poll_base0 + (size_t)(t & 1) * MB_PAR;
      const uint32_t hi = (uint32_t)t << 16;
      uint4 x[16];
      bool got = false;

      if (fast) {
        // ---- fast poll: 16 dwordx4 agent-scope (sc1) loads in flight ----
        int it = 0;
        for (;;) {
#define PL_(I, OFF) \
          asm volatile("global_load_dwordx4 %0, %1, off offset:" OFF " sc1" \
                       : "=&v"(x[I]) : "v"(pb) : "memory")
          PL_(0, "0");   PL_(1, "16");  PL_(2, "32");  PL_(3, "48");
          PL_(4, "64");  PL_(5, "80");  PL_(6, "96");  PL_(7, "112");
          PL_(8, "128"); PL_(9, "144"); PL_(10, "160"); PL_(11, "176");
          PL_(12, "192"); PL_(13, "208"); PL_(14, "224"); PL_(15, "240");
#undef PL_
          asm volatile("s_waitcnt vmcnt(0)" ::: "memory");
          __builtin_amdgcn_sched_barrier(0);
          uint32_t m = 0;
#pragma unroll
          for (int k = 0; k < 16; ++k) {
            m |= (x[k].x ^ hi); m |= (x[k].y ^ hi);
            m |= (x[k].z ^ hi); m |= (x[k].w ^ hi);
          }
          if (m < 0x10000u) { got = true; break; }   // all 64 tags == t
          if (++it >= 256) break;
        }
        if (!got) fast = false;   // sticky demotion for this lane
      }

      if (!got) {
        // ---- reliable: batched agent-scope atomic loads, all-or-retry ----
        int guard = 0;
        for (;;) {
          uint32_t m = 0;
#pragma unroll
          for (int k = 0; k < 16; ++k) {
            uint32_t a0 = __hip_atomic_load(&pb[4 * k + 0], __ATOMIC_RELAXED, __HIP_MEMORY_SCOPE_AGENT);
            uint32_t a1 = __hip_atomic_load(&pb[4 * k + 1], __ATOMIC_RELAXED, __HIP_MEMORY_SCOPE_AGENT);
            uint32_t a2 = __hip_atomic_load(&pb[4 * k + 2], __ATOMIC_RELAXED, __HIP_MEMORY_SCOPE_AGENT);
            uint32_t a3 = __hip_atomic_load(&pb[4 * k + 3], __ATOMIC_RELAXED, __HIP_MEMORY_SCOPE_AGENT);
            x[k].x = a0; x[k].y = a1; x[k].z = a2; x[k].w = a3;
            m |= (a0 ^ hi); m |= (a1 ^ hi); m |= (a2 ^ hi); m |= (a3 ^ hi);
          }
          if (m < 0x10000u) break;
          if (++guard > (1 << 20)) break;   // hang-safety only
        }
      }

      // issue t+2 ig prefetch now (post-detection: never stalls a poll)
      if (t + 2 < T_) {
        const size_t fb = igbase + 2 * (size_t)G3_;
        fr = ig16[fb + j];
        fz = ig16[fb + j + H_];
        fn = ig16[fb + j + 2 * H_];
      }

      // ---- pack h pairs and dot (3 gates x 32 fdot2, 2 chains each) ----
      uint32_t ph[32];
#pragma unroll
      for (int k = 0; k < 16; ++k) {
        ph[2 * k]     = (x[k].x & 0xFFFFu) | (x[k].y << 16);
        ph[2 * k + 1] = (x[k].z & 0xFFFFu) | (x[k].w << 16);
      }
      float ar0 = 0.0f, az0 = 0.0f, an0 = 0.0f;
      float ar1 = 0.0f, az1 = 0.0f, an1 = 0.0f;
#pragma unroll
      for (int k = 0; k < 16; ++k) {
        ar0 = fdot2f(wr[k], ph[k], ar0);
        az0 = fdot2f(wz[k], ph[k], az0);
        an0 = fdot2f(wn[k], ph[k], an0);
      }
#pragma unroll
      for (int k = 16; k < 32; ++k) {
        ar1 = fdot2f(wr[k], ph[k], ar1);
        az1 = fdot2f(wz[k], ph[k], az1);
        an1 = fdot2f(wn[k], ph[k], an1);
      }
      ar = ar0 + ar1; az = az0 + az1; an = an0 + an1;
      // reduce across the 8 K-slice lanes (lanes 8c..8c+7, q fastest-varying)
      ar += __shfl_xor(ar, 1); ar += __shfl_xor(ar, 2); ar += __shfl_xor(ar, 4);
      az += __shfl_xor(az, 1); az += __shfl_xor(az, 2); az += __shfl_xor(az, 4);
      an += __shfl_xor(an, 1); an += __shfl_xor(an, 2); an += __shfl_xor(an, 4);
    } else {
      ar = az = an = 0.0f;   // h0 = 0
      if (t + 2 < T_) {
        const size_t fb = igbase + 2 * (size_t)G3_;
        fr = ig16[fb + j];
        fz = ig16[fb + j + H_];
        fn = ig16[fb + j + 2 * H_];
      }
    }

    // ---- gates (computed redundantly by all 8 q-lanes of a column) ----
    const float igr = h2f(cr), igz = h2f(cz), ign = h2f(cn);
    const float r = sigmoidf_(igr + ar);
    const float z = sigmoidf_(igz + az);
    const float n = tanhf_(ign + r * (an + bnj));
    const float hnew = n + z * (hprev - n);
    hprev = hnew;

    // ---- publish (1 tagged agent store per column) + out ----
    if (q == 0) {
      const uint32_t wv = ((uint32_t)(t + 1) << 16) | f16bits(hnew);
      __hip_atomic_store(box0 + (size_t)((t + 1) & 1) * MB_PAR + j, wv,
                         __ATOMIC_RELAXED, __HIP_MEMORY_SCOPE_AGENT);
      out[((size_t)b * T_ + t) * H_ + j] = hnew;
    }

    // rotate ig pipeline
    cr = nr; cz = nz; cn = nn2;
    nr = fr; nz = fz; nn2 = fn;
    igbase += G3_;
  }
}

// ---------------- Fallback: naive (only if ws too small) ----------------
__global__ void __launch_bounds__(512) naive_kernel(const float* __restrict__ xs,
                                                    const float* __restrict__ Wih,
                                                    const float* __restrict__ Whh,
                                                    const float* __restrict__ bias,
                                                    const float* __restrict__ bn,
                                                    float* __restrict__ out) {
  const int b = blockIdx.x;
  const int j = threadIdx.x;
  __shared__ float h[H_];
  __shared__ float xr[D_];
  h[j] = 0.0f;
  __syncthreads();
  for (int t = 0; t < T_; ++t) {
    if (j < D_) xr[j] = xs[((size_t)b * T_ + t) * D_ + j];
    __syncthreads();
    float a[2];
#pragma unroll
    for (int g = 0; g < 2; ++g) {
      const int row = j + g * H_;
      float ssum = bias[row];
      const float* wi = Wih + (size_t)row * D_;
      for (int d = 0; d < D_; ++d) ssum = fmaf(wi[d], xr[d], ssum);
      const float* wh = Whh + (size_t)row * H_;
      for (int kk = 0; kk < H_; ++kk) ssum = fmaf(wh[kk], h[kk], ssum);
      a[g] = ssum;
    }
    const float r = sigmoidf_(a[0]);
    const float z = sigmoidf_(a[1]);
    float i_n = bias[j + 2 * H_];
    {
      const float* wi = Wih + (size_t)(j + 2 * H_) * D_;
      for (int d = 0; d < D_; ++d) i_n = fmaf(wi[d], xr[d], i_n);
    }
    float h_n = 0.0f;
    {
      const float* wh = Whh + (size_t)(j + 2 * H_) * H_;
      for (int kk = 0; kk < H_; ++kk) h_n = fmaf(wh[kk], h[kk], h_n);
    }
    const float nn = tanhf_(i_n + r * (h_n + bn[j]));
    const float hnew = nn + z * (h[j] - nn);
    __syncthreads();
    h[j] = hnew;
    out[((size_t)b * T_ + t) * H_ + j] = hnew;
  }
}

extern "C" void kernel_launch(void* const* d_in, const int* in_sizes, int n_in,
                              void* d_out, int out_size, void* d_ws, size_t ws_size,
                              hipStream_t stream) {
  const float* xs  = (const float*)d_in[0];
  const float* Wih = (const float*)d_in[1];
  const float* Whh = (const float*)d_in[2];
  const float* bia = (const float*)d_in[3];
  const float* bnp = (const float*)d_in[4];
  float* out = (float*)d_out;

  if (ws_size >= WS_NEED) {
    char* ws = (char*)d_ws;
    _Float16* igp = (_Float16*)(ws + OFF_IG);
    float* wtp = (float*)(ws + OFF_WT);
    uint32_t* mbp = (uint32_t*)(ws + OFF_MB);

    // zero tag mailbox (stale-tag kill across graph replays)
    hipMemsetAsync(mbp, 0, 2 * MB_PAR * sizeof(uint32_t), stream);

    wt_kernel<<<dim3(384), dim3(256), 0, stream>>>(Wih, (float4*)wtp);
    ig_kernel<<<dim3((B_ * T_) / 16), dim3(256), 0, stream>>>(xs, wtp, bia, igp);
    rec_kernel<<<dim3(256), dim3(256), 0, stream>>>(igp, Whh, bnp, mbp, out);
  } else {
    naive_kernel<<<dim3(B_), dim3(H_), 0, stream>>>(xs, Wih, Whh, bia, bnp, out);
  }
}

// Round 8
// 7599.433 us; speedup vs baseline: 4.8129x; 4.8129x over previous
//
#include <hip/hip_runtime.h>
#include <stdint.h>
#include <stddef.h>

#define B_ 16
#define T_ 4096
#define D_ 256
#define H_ 512
#define G3_ 1536

// ws layout
#define OFF_IG   ((size_t)0)                       // igates f16: 65536*1536*2 = 201326592
#define OFF_WT   ((size_t)201326592)               // W_ih^T packed float4: 256*1536*4 = 1572864
#define OFF_MB   ((size_t)202899456)               // mailboxes: 2*16*8*512*4 = 524288
#define WS_NEED  ((size_t)203423744)

#define PAR_STRIDE ((size_t)B_ * 8 * 512)           // words per parity buffer

typedef _Float16 h2_t __attribute__((ext_vector_type(2)));

#if defined(__has_builtin)
#if __has_builtin(__builtin_amdgcn_fdot2)
#define HAVE_FDOT2 1
#endif
#endif

__device__ __forceinline__ float fdot2f(uint32_t w, uint32_t h, float acc) {
  union { uint32_t u; h2_t v; } a, b;
  a.u = w; b.u = h;
#ifdef HAVE_FDOT2
  return __builtin_amdgcn_fdot2(a.v, b.v, acc, false);
#else
  return fmaf((float)a.v.x, (float)b.v.x, fmaf((float)a.v.y, (float)b.v.y, acc));
#endif
}

__device__ __forceinline__ uint32_t packh2(float a, float b) {
  union { h2_t v; uint32_t u; } x;
  x.v.x = (_Float16)a; x.v.y = (_Float16)b;
  return x.u;
}

__device__ __forceinline__ uint32_t f16bits(float a) {
  union { _Float16 h; uint16_t u; } x;
  x.h = (_Float16)a;
  return (uint32_t)x.u;
}

__device__ __forceinline__ float h2f(uint16_t u) {
  union { _Float16 h; uint16_t u; } x;
  x.u = u;
  return (float)x.h;
}

__device__ __forceinline__ float sigmoidf_(float x) {
  return 1.0f / (1.0f + __expf(-x));
}

__device__ __forceinline__ float tanhf_(float x) {
  x = fminf(fmaxf(x, -15.0f), 15.0f);
  float e = __expf(-2.0f * x);
  return (1.0f - e) / (1.0f + e);
}

// ---------------- Kernel 1: transpose+pack W_ih into [d/4][g] float4 ----------------
__global__ void __launch_bounds__(256) wt_kernel(const float* __restrict__ W, float4* __restrict__ Wt4) {
  int idx = blockIdx.x * 256 + threadIdx.x;   // over 1536*64
  if (idx >= G3_ * 64) return;
  int g = idx % G3_;
  int d4 = idx / G3_;
  float4 v = *(const float4*)(W + (size_t)g * D_ + 4 * d4);
  Wt4[(size_t)d4 * G3_ + g] = v;
}

// ---------------- Kernel 2: igates = xs @ W_ih^T + b  -> f16 ----------------
__global__ void __launch_bounds__(256) ig_kernel(const float* __restrict__ xs,
                                                 const float* __restrict__ Wt,
                                                 const float* __restrict__ bias,
                                                 _Float16* __restrict__ ig) {
  __shared__ float xls[16 * 256];
  const int m0 = blockIdx.x * 16;
  const int tid = threadIdx.x;

  const float4* xsrc = (const float4*)(xs + (size_t)m0 * D_);
  float4* xdst = (float4*)xls;
#pragma unroll
  for (int k = 0; k < 4; ++k) xdst[tid + 256 * k] = xsrc[tid + 256 * k];
  __syncthreads();

  float acc[6][16];
#pragma unroll
  for (int k = 0; k < 6; ++k)
#pragma unroll
    for (int m = 0; m < 16; ++m) acc[k][m] = 0.0f;

  const float4* Wt4 = (const float4*)Wt;
  const float4* lds4 = (const float4*)xls;

  for (int d4 = 0; d4 < 64; ++d4) {
    float4 w[6];
#pragma unroll
    for (int k = 0; k < 6; ++k) w[k] = Wt4[(size_t)d4 * G3_ + tid + 256 * k];
#pragma unroll
    for (int m = 0; m < 16; ++m) {
      float4 xv = lds4[m * 64 + d4];
#pragma unroll
      for (int k = 0; k < 6; ++k) {
        acc[k][m] = fmaf(w[k].x, xv.x, acc[k][m]);
        acc[k][m] = fmaf(w[k].y, xv.y, acc[k][m]);
        acc[k][m] = fmaf(w[k].z, xv.z, acc[k][m]);
        acc[k][m] = fmaf(w[k].w, xv.w, acc[k][m]);
      }
    }
  }

#pragma unroll
  for (int k = 0; k < 6; ++k) {
    float bb = bias[tid + 256 * k];
#pragma unroll
    for (int m = 0; m < 16; ++m) {
      ig[(size_t)(m0 + m) * G3_ + tid + 256 * k] = (_Float16)(acc[k][m] + bb);
    }
  }
}

// ---------------- Kernel 3: persistent recurrence ----------------
// 256 WGs x 256 threads, 1 WG/CU. WG wg: batch b = wg>>4, sub s = wg&15 owns
// columns [s*32, s*32+32). Thread: q = tid&7 (K-slice of 64), c = tid>>3,
// j = s*32 + c. Weights: rows {j, j+512, j+1024} x K[q*64,+64) = 96 packed
// f16-pair VGPRs.
// Exchange: 8 mailbox copies per batch (each 512 tagged words
// (tag<<16)|f16(h)), double-buffered by parity. Producer: lane q agent-stores
// column j into copy q (1 store/thread). Consumer: WG s polls copy s>>1
// (2 pollers/word -> no hot-line storm; R7 lesson); each thread polls ITS 2
// words (2*tid, 2*tid+1) with ONE dwordx2 sc1 (agent-scope) load per round.
// Detection -> LDS redistribute (padded [8][36]) -> ONE barrier/step
// (double-buffered LDS; overwrite of tag t+2 happens-after all barrier(t)).
// ig prefetch 2-deep, issued POST-detection so no poll vmcnt drains HBM loads.
__global__ void __launch_bounds__(256, 1) rec_kernel(const _Float16* __restrict__ ig,
                                                     const float* __restrict__ Whh,
                                                     const float* __restrict__ bn,
                                                     uint32_t* __restrict__ mb,
                                                     float* __restrict__ out) {
  const int tid = threadIdx.x;
  const int wg = blockIdx.x;       // 0..255
  const int b = wg >> 4;           // 0..15
  const int s = wg & 15;           // 0..15
  const int q = tid & 7;           // K-slice
  const int c = tid >> 3;          // 0..31
  const int j = s * 32 + c;        // 0..511

  // ---- load + pack weights into registers (96 dwords) ----
  uint32_t wr[32], wz[32], wn[32];
  {
    const float4* s0 = (const float4*)(Whh + (size_t)j * H_ + q * 64);
    const float4* s1 = (const float4*)(Whh + (size_t)(j + H_) * H_ + q * 64);
    const float4* s2 = (const float4*)(Whh + (size_t)(j + 2 * H_) * H_ + q * 64);
#pragma unroll
    for (int i = 0; i < 16; ++i) {
      float4 v0 = s0[i]; wr[2 * i] = packh2(v0.x, v0.y); wr[2 * i + 1] = packh2(v0.z, v0.w);
      float4 v1 = s1[i]; wz[2 * i] = packh2(v1.x, v1.y); wz[2 * i + 1] = packh2(v1.z, v1.w);
      float4 v2 = s2[i]; wn[2 * i] = packh2(v2.x, v2.y); wn[2 * i + 1] = packh2(v2.z, v2.w);
    }
  }
  const float bnj = bn[j];

  // double-buffered padded LDS h-pairs: [parity][8 regions][32 + 4 pad]
  __shared__ uint32_t hl[2][8][36];

  // mailbox addresses
  uint32_t* mypoll = mb + ((size_t)b * 8 + (s >> 1)) * 512 + 2 * tid;  // my 2 words
  uint32_t* mypub  = mb + ((size_t)b * 8 + q) * 512 + j;               // copy q, word j

  const uint16_t* ig16 = (const uint16_t*)ig;
  size_t igbase = (size_t)b * T_ * G3_;

  // ig pipeline: cur(t), nxt(t+1) preloaded; fut(t+2) issued post-detection
  uint16_t cr = ig16[igbase + j];
  uint16_t cz = ig16[igbase + j + H_];
  uint16_t cn = ig16[igbase + j + 2 * H_];
  uint16_t nr = ig16[igbase + G3_ + j];
  uint16_t nz = ig16[igbase + G3_ + j + H_];
  uint16_t nn2 = ig16[igbase + G3_ + j + 2 * H_];

  float hprev = 0.0f;

  for (int t = 0; t < T_; ++t) {
    uint16_t fr = 0, fz = 0, fn = 0;

    if (t > 0) {
      // ---- poll my 2 words: one dwordx2 agent-scope load per round ----
      uint32_t* pb = mypoll + (size_t)(t & 1) * PAR_STRIDE;
      const uint32_t hi = (uint32_t)t << 16;
      uint32_t a0, a1;
      int it = 0;
      for (;;) {
        unsigned long long vv;
        asm volatile("global_load_dwordx2 %0, %1, off sc1\n\ts_waitcnt vmcnt(0)"
                     : "=v"(vv) : "v"(pb) : "memory");
        a0 = (uint32_t)vv;
        a1 = (uint32_t)(vv >> 32);
        if ((((a0 ^ hi) | (a1 ^ hi)) >> 16) == 0u) break;   // both tags == t
        if (++it > (1 << 20)) { a0 = a1 = 0x7C00u; break; } // visible poison, no hang
      }
      // stage pair into LDS: slot tid -> region tid>>5, offset tid&31
      hl[t & 1][tid >> 5][tid & 31] = (a0 & 0xFFFFu) | (a1 << 16);

      // issue t+2 ig prefetch now (post-detection: polls never drain it)
      if (t + 2 < T_) {
        const size_t fb = igbase + 2 * (size_t)G3_;
        fr = ig16[fb + j];
        fz = ig16[fb + j + H_];
        fn = ig16[fb + j + 2 * H_];
      }
    } else {
      const size_t fb = igbase + 2 * (size_t)G3_;
      fr = ig16[fb + j];
      fz = ig16[fb + j + H_];
      fn = ig16[fb + j + 2 * H_];
    }

    __syncthreads();   // single barrier per step (double-buffered hl)

    float ar = 0.0f, az = 0.0f, an = 0.0f;
    if (t > 0) {
      // ---- dot: 3 gates x 32 fdot2, 2 chains per gate; conflict-free b128 ----
      const uint4* hq = (const uint4*)hl[t & 1][q];
      uint4 hv[8];
#pragma unroll
      for (int i = 0; i < 8; ++i) hv[i] = hq[i];
      float ar0 = 0.0f, az0 = 0.0f, an0 = 0.0f;
      float ar1 = 0.0f, az1 = 0.0f, an1 = 0.0f;
#pragma unroll
      for (int i = 0; i < 4; ++i) {
        ar0 = fdot2f(wr[4 * i + 0], hv[i].x, ar0); az0 = fdot2f(wz[4 * i + 0], hv[i].x, az0); an0 = fdot2f(wn[4 * i + 0], hv[i].x, an0);
        ar0 = fdot2f(wr[4 * i + 1], hv[i].y, ar0); az0 = fdot2f(wz[4 * i + 1], hv[i].y, az0); an0 = fdot2f(wn[4 * i + 1], hv[i].y, an0);
        ar0 = fdot2f(wr[4 * i + 2], hv[i].z, ar0); az0 = fdot2f(wz[4 * i + 2], hv[i].z, az0); an0 = fdot2f(wn[4 * i + 2], hv[i].z, an0);
        ar0 = fdot2f(wr[4 * i + 3], hv[i].w, ar0); az0 = fdot2f(wz[4 * i + 3], hv[i].w, az0); an0 = fdot2f(wn[4 * i + 3], hv[i].w, an0);
      }
#pragma unroll
      for (int i = 4; i < 8; ++i) {
        ar1 = fdot2f(wr[4 * i + 0], hv[i].x, ar1); az1 = fdot2f(wz[4 * i + 0], hv[i].x, az1); an1 = fdot2f(wn[4 * i + 0], hv[i].x, an1);
        ar1 = fdot2f(wr[4 * i + 1], hv[i].y, ar1); az1 = fdot2f(wz[4 * i + 1], hv[i].y, az1); an1 = fdot2f(wn[4 * i + 1], hv[i].y, an1);
        ar1 = fdot2f(wr[4 * i + 2], hv[i].z, ar1); az1 = fdot2f(wz[4 * i + 2], hv[i].z, az1); an1 = fdot2f(wn[4 * i + 2], hv[i].z, an1);
        ar1 = fdot2f(wr[4 * i + 3], hv[i].w, ar1); az1 = fdot2f(wz[4 * i + 3], hv[i].w, az1); an1 = fdot2f(wn[4 * i + 3], hv[i].w, an1);
      }
      ar = ar0 + ar1; az = az0 + az1; an = an0 + an1;
      // reduce across the 8 K-slice lanes (lanes 8c..8c+7)
      ar += __shfl_xor(ar, 1); ar += __shfl_xor(ar, 2); ar += __shfl_xor(ar, 4);
      az += __shfl_xor(az, 1); az += __shfl_xor(az, 2); az += __shfl_xor(az, 4);
      an += __shfl_xor(an, 1); an += __shfl_xor(an, 2); an += __shfl_xor(an, 4);
    }

    // ---- gates (redundant on all 8 q-lanes of a column) ----
    const float igr = h2f(cr), igz = h2f(cz), ign = h2f(cn);
    const float r = sigmoidf_(igr + ar);
    const float z = sigmoidf_(igz + az);
    const float n = tanhf_(ign + r * (an + bnj));
    const float hnew = n + z * (hprev - n);
    hprev = hnew;

    // ---- publish: 1 tagged agent store per thread (lane q -> copy q) ----
    const uint32_t wv = ((uint32_t)(t + 1) << 16) | f16bits(hnew);
    __hip_atomic_store(mypub + (size_t)((t + 1) & 1) * PAR_STRIDE, wv,
                       __ATOMIC_RELAXED, __HIP_MEMORY_SCOPE_AGENT);

    if (q == 0) {
      out[((size_t)b * T_ + t) * H_ + j] = hnew;
    }

    // rotate ig pipeline
    cr = nr; cz = nz; cn = nn2;
    nr = fr; nz = fz; nn2 = fn;
    igbase += G3_;
  }
}

// ---------------- Fallback: naive (only if ws too small) ----------------
__global__ void __launch_bounds__(512) naive_kernel(const float* __restrict__ xs,
                                                    const float* __restrict__ Wih,
                                                    const float* __restrict__ Whh,
                                                    const float* __restrict__ bias,
                                                    const float* __restrict__ bn,
                                                    float* __restrict__ out) {
  const int b = blockIdx.x;
  const int j = threadIdx.x;
  __shared__ float h[H_];
  __shared__ float xr[D_];
  h[j] = 0.0f;
  __syncthreads();
  for (int t = 0; t < T_; ++t) {
    if (j < D_) xr[j] = xs[((size_t)b * T_ + t) * D_ + j];
    __syncthreads();
    float a[2];
#pragma unroll
    for (int g = 0; g < 2; ++g) {
      const int row = j + g * H_;
      float ssum = bias[row];
      const float* wi = Wih + (size_t)row * D_;
      for (int d = 0; d < D_; ++d) ssum = fmaf(wi[d], xr[d], ssum);
      const float* wh = Whh + (size_t)row * H_;
      for (int kk = 0; kk < H_; ++kk) ssum = fmaf(wh[kk], h[kk], ssum);
      a[g] = ssum;
    }
    const float r = sigmoidf_(a[0]);
    const float z = sigmoidf_(a[1]);
    float i_n = bias[j + 2 * H_];
    {
      const float* wi = Wih + (size_t)(j + 2 * H_) * D_;
      for (int d = 0; d < D_; ++d) i_n = fmaf(wi[d], xr[d], i_n);
    }
    float h_n = 0.0f;
    {
      const float* wh = Whh + (size_t)(j + 2 * H_) * H_;
      for (int kk = 0; kk < H_; ++kk) h_n = fmaf(wh[kk], h[kk], h_n);
    }
    const float nn = tanhf_(i_n + r * (h_n + bn[j]));
    const float hnew = nn + z * (h[j] - nn);
    __syncthreads();
    h[j] = hnew;
    out[((size_t)b * T_ + t) * H_ + j] = hnew;
  }
}

extern "C" void kernel_launch(void* const* d_in, const int* in_sizes, int n_in,
                              void* d_out, int out_size, void* d_ws, size_t ws_size,
                              hipStream_t stream) {
  const float* xs  = (const float*)d_in[0];
  const float* Wih = (const float*)d_in[1];
  const float* Whh = (const float*)d_in[2];
  const float* bia = (const float*)d_in[3];
  const float* bnp = (const float*)d_in[4];
  float* out = (float*)d_out;

  if (ws_size >= WS_NEED) {
    char* ws = (char*)d_ws;
    _Float16* igp = (_Float16*)(ws + OFF_IG);
    float* wtp = (float*)(ws + OFF_WT);
    uint32_t* mbp = (uint32_t*)(ws + OFF_MB);

    // zero tag mailboxes (stale-tag kill across graph replays)
    hipMemsetAsync(mbp, 0, 2 * PAR_STRIDE * sizeof(uint32_t), stream);

    wt_kernel<<<dim3(384), dim3(256), 0, stream>>>(Wih, (float4*)wtp);
    ig_kernel<<<dim3((B_ * T_) / 16), dim3(256), 0, stream>>>(xs, wtp, bia, igp);
    rec_kernel<<<dim3(256), dim3(256), 0, stream>>>(igp, Whh, bnp, mbp, out);
  } else {
    naive_kernel<<<dim3(B_), dim3(H_), 0, stream>>>(xs, Wih, Whh, bia, bnp, out);
  }
}